// Round 9
// baseline (12549.142 us; speedup 1.0000x reference)
//
#include <hip/hip_runtime.h>
#include <hip/hip_bf16.h>
#include <stdint.h>

// Problem dims
#define BB 64
#define SS 512
#define EE 256
#define HH 1024
#define VV 128

typedef __attribute__((ext_vector_type(8))) short short8;
typedef __attribute__((ext_vector_type(4))) float floatx4;

// ---- LDS layout ----
#define LDS_UFRAG 0                 // 3 gates * 32 ktiles * 64 lanes * 16B = 98304 (shared, read-only)
#define LDS_TOK   98304             // 4 groups * 16 rows * 512 u8 = 32768
#define LDS_XFER  131072            // 4 waves * 1024B private transpose tiles
#define LDS_TOTAL 135168

// ---- workspace layout (bytes) ----
#define WS_TABLE  0                  // 128*3*1024 fp32 = 1572864
#define WS_RH     1572864            // 64*1024 bf16 = 131072
#define WS_FLAGS  1703936            // flagsA[4*64], flagsB[4*64] ints = 2048 (memset region)
#define WS_OUTS   2097152            // 512*64*1024 bf16 = 67108864

__device__ __forceinline__ unsigned short f2bf(float f) {
  union { float f; unsigned int i; } x; x.f = f;
  unsigned int r = x.i + 0x7fffu + ((x.i >> 16) & 1u);
  return (unsigned short)(r >> 16);
}
__device__ __forceinline__ unsigned long long pack4bf(float a, float b, float c, float d) {
  unsigned int lo = ((unsigned int)f2bf(b) << 16) | f2bf(a);
  unsigned int hi = ((unsigned int)f2bf(d) << 16) | f2bf(c);
  return ((unsigned long long)hi << 32) | lo;
}
// sc1 store: lands at the cross-XCD coherence point, never dirties L2.
__device__ __forceinline__ void st_agent_b64(unsigned long long* p, unsigned long long v) {
  __hip_atomic_store(p, v, __ATOMIC_RELAXED, __HIP_MEMORY_SCOPE_AGENT);
}

// table[v][g][j] = sum_e emb[v][e] * W_g[j][e] + 2*b_g[j]   (fp32 in, fp32 out)
__global__ void __launch_bounds__(256)
table_kernel(const float* __restrict__ emb,
             const float* __restrict__ Wr, const float* __restrict__ br,
             const float* __restrict__ Wz, const float* __restrict__ bz,
             const float* __restrict__ Wh, const float* __restrict__ bh,
             float* __restrict__ table) {
  int id = blockIdx.x * 256 + threadIdx.x;          // 393216 exact
  int v = id / 3072;
  int rem = id - v * 3072;
  int g = rem >> 10;
  int j = rem & 1023;
  const float* W  = (g == 0) ? Wr : (g == 1) ? Wz : Wh;
  const float* bb = (g == 0) ? br : (g == 1) ? bz : bh;
  const float4* ev = (const float4*)(emb + (size_t)v * EE);
  const float4* wv = (const float4*)(W + (size_t)j * EE);
  float acc = 2.f * bb[j];                          // faithful: bias added twice
  for (int e = 0; e < EE / 4; ++e) {
    float4 a = ev[e], b4 = wv[e];
    acc += a.x * b4.x + a.y * b4.y + a.z * b4.z + a.w * b4.w;
  }
  table[id] = acc;
}

// Per-WAVE coalesced bypass poll over one group's 64 flags ("=&v" early-clobber!).
__device__ __forceinline__ void poll_flags(const int* flags, int tgt, int lane) {
  const char* fp = (const char*)flags + (lane & 15) * 16;
  for (;;) {
    uint4 f;
    asm volatile("global_load_dwordx4 %0, %1, off sc0 sc1\n\t"
                 "s_waitcnt vmcnt(0)"
                 : "=&v"(f) : "v"(fp) : "memory");
    bool ok = ((int)f.x >= tgt) & ((int)f.y >= tgt) &
              ((int)f.z >= tgt) & ((int)f.w >= tgt);
    if (__all(ok)) break;
    __builtin_amdgcn_s_sleep(1);
  }
}

// Persistent cooperative GRU. 64 WGs x 256 threads. WG = 16-col slice; WAVE g
// owns batch-group g end-to-end (full K=1024, no cross-wave reduction, no
// intra-step barriers). State (h, z) in registers; U shared read-only in LDS.
__global__ void __launch_bounds__(256, 1)
gru_kernel(const int* __restrict__ x,
           const float* __restrict__ Ur, const float* __restrict__ Uz,
           const float* __restrict__ Uh,
           const float* __restrict__ table,
           unsigned short* __restrict__ outs,     // [S][B][H] bf16 (sc1-written, cached reads)
           unsigned short* __restrict__ rhbuf,    // [B][H] bf16 (sc1-written, bypass reads)
           float* __restrict__ hlast,             // [B][H] fp32 -> d_out tail
           int* __restrict__ flagsA, int* __restrict__ flagsB) {  // [4][64]
  extern __shared__ char smem[];
  const int tid = threadIdx.x;
  const int lane = tid & 63;
  const int g = tid >> 6;            // wave index == batch-group (rows g*16..g*16+15)
  const int wg = blockIdx.x;         // 0..63 column slice
  const int j0 = wg << 4;
  const int j = lane & 15;
  const int qb = (lane >> 4) * 4;    // C-layout: reg i holds row qb+i, col j

  unsigned char* toks = (unsigned char*)(smem + LDS_TOK + g * 8192);   // [16][512]
  float* xfer = (float*)(smem + LDS_XFER + g * 1024);                  // wave-private

  // ---- init: U (fp32) -> LDS bf16 B-frags (shared); tokens per group ----
  {
    const float* Us[3] = {Ur, Uz, Uh};
    for (int c = g * 24; c < g * 24 + 24; ++c) {     // 96 (gate,ktile) chunks / 4 waves
      int gt = c >> 5, kt = c & 31;
      // B-frag: lane holds U[j0+(lane&15)][kt*32 + (lane>>4)*8 + 0..7]
      const float* src = Us[gt] + (size_t)(j0 + j) * HH + kt * 32 + (lane >> 4) * 8;
      float4 f0 = ((const float4*)src)[0];
      float4 f1 = ((const float4*)src)[1];
      short8 frag;
      frag[0] = (short)f2bf(f0.x); frag[1] = (short)f2bf(f0.y);
      frag[2] = (short)f2bf(f0.z); frag[3] = (short)f2bf(f0.w);
      frag[4] = (short)f2bf(f1.x); frag[5] = (short)f2bf(f1.y);
      frag[6] = (short)f2bf(f1.z); frag[7] = (short)f2bf(f1.w);
      *(short8*)(smem + ((gt * 32 + kt) * 64 + lane) * 16) = frag;
    }
    for (int i = lane; i < 16 * SS; i += 64) {
      int b = i >> 9, tt = i & 511;
      toks[i] = (unsigned char)x[(size_t)(g * 16 + b) * SS + tt];
    }
  }
  __syncthreads();   // the ONLY barrier: U/toks ready; waves are independent after

  floatx4 h_own = {0, 0, 0, 0};      // fp32 master copy, registers (C-layout)
  float zz0, zz1, zz2, zz3;

  for (int t = 0; t < SS; ++t) {
    // ================= phase A : r, z (full K in this wave) =================
    floatx4 accr = {0,0,0,0}, accz = {0,0,0,0};
    if (t > 0) {
      poll_flags(flagsB + g * 64, t, lane);
      // A-frags straight from global (cached; write-once lines, first touch after flag).
      // lane: row g*16+j, k = kt*32 + (lane>>4)*8 -> 16 rows x 64B contiguous per load.
      const unsigned short* hb =
          outs + ((size_t)(t - 1) * BB + g * 16 + j) * HH + (lane >> 4) * 8;
      uint4 fr[32];
#pragma unroll
      for (int kt = 0; kt < 32; ++kt) fr[kt] = *(const uint4*)(hb + kt * 32);
#pragma unroll
      for (int kt = 0; kt < 32; ++kt) {
        short8 a   = *(short8*)&fr[kt];
        short8 br_ = *(const short8*)(smem + ((0 * 32 + kt) * 64 + lane) * 16);
        short8 bz_ = *(const short8*)(smem + ((1 * 32 + kt) * 64 + lane) * 16);
        accr = __builtin_amdgcn_mfma_f32_16x16x32_bf16(a, br_, accr, 0, 0, 0);
        accz = __builtin_amdgcn_mfma_f32_16x16x32_bf16(a, bz_, accz, 0, 0, 0);
      }
    }
    // epilogue A: r,z; rh -> xfer -> packed sc1 store; release flag
    {
      float rh0, rh1, rh2, rh3;
#pragma unroll
      for (int i = 0; i < 4; ++i) {
        int b = qb + i;
        int tok = toks[b * 512 + t];
        float xr = table[tok * 3072 + j0 + j];
        float xz = table[tok * 3072 + 1024 + j0 + j];
        float r = 1.f / (1.f + __expf(-(accr[i] + xr)));
        float z = 1.f / (1.f + __expf(-(accz[i] + xz)));
        float rh = r * h_own[i];
        if (i == 0) { zz0 = z; rh0 = rh; } else if (i == 1) { zz1 = z; rh1 = rh; }
        else if (i == 2) { zz2 = z; rh2 = rh; } else { zz3 = z; rh3 = rh; }
      }
      xfer[(qb + 0) * 16 + j] = rh0;
      xfer[(qb + 1) * 16 + j] = rh1;
      xfer[(qb + 2) * 16 + j] = rh2;
      xfer[(qb + 3) * 16 + j] = rh3;
      asm volatile("s_waitcnt lgkmcnt(0)" ::: "memory");   // in-wave cross-lane LDS RAW
      int row = lane >> 2, c0 = (lane & 3) * 4;
      unsigned long long pk = pack4bf(xfer[row * 16 + c0 + 0], xfer[row * 16 + c0 + 1],
                                      xfer[row * 16 + c0 + 2], xfer[row * 16 + c0 + 3]);
      st_agent_b64((unsigned long long*)(rhbuf + (size_t)(g * 16 + row) * HH + j0 + c0), pk);
      if (lane == 0)   // release: vmcnt(0) drains this wave's sc1 stores first
        __hip_atomic_store(flagsA + g * 64 + wg, t + 1, __ATOMIC_RELEASE, __HIP_MEMORY_SCOPE_AGENT);
    }

    // ================= phase B : h_tilde, h_new =================
    poll_flags(flagsA + g * 64, t + 1, lane);
    floatx4 acch = {0,0,0,0};
    {
      // rh addresses reused every step -> bypass L2: 32x dwordx4 sc0 sc1, one drain.
      const char* rb = (const char*)(rhbuf + (size_t)(g * 16 + j) * HH + (lane >> 4) * 8);
      uint4 q00,q01,q02,q03,q04,q05,q06,q07,q08,q09,q10,q11,q12,q13,q14,q15;
      uint4 q16,q17,q18,q19,q20,q21,q22,q23,q24,q25,q26,q27,q28,q29,q30,q31;
      asm volatile(
        "global_load_dwordx4 %0, %8, off sc0 sc1\n\t"
        "global_load_dwordx4 %1, %8, off offset:64 sc0 sc1\n\t"
        "global_load_dwordx4 %2, %8, off offset:128 sc0 sc1\n\t"
        "global_load_dwordx4 %3, %8, off offset:192 sc0 sc1\n\t"
        "global_load_dwordx4 %4, %8, off offset:256 sc0 sc1\n\t"
        "global_load_dwordx4 %5, %8, off offset:320 sc0 sc1\n\t"
        "global_load_dwordx4 %6, %8, off offset:384 sc0 sc1\n\t"
        "global_load_dwordx4 %7, %8, off offset:448 sc0 sc1"
        : "=&v"(q00),"=&v"(q01),"=&v"(q02),"=&v"(q03),
          "=&v"(q04),"=&v"(q05),"=&v"(q06),"=&v"(q07)
        : "v"(rb) : "memory");
      asm volatile(
        "global_load_dwordx4 %0, %8, off offset:512 sc0 sc1\n\t"
        "global_load_dwordx4 %1, %8, off offset:576 sc0 sc1\n\t"
        "global_load_dwordx4 %2, %8, off offset:640 sc0 sc1\n\t"
        "global_load_dwordx4 %3, %8, off offset:704 sc0 sc1\n\t"
        "global_load_dwordx4 %4, %8, off offset:768 sc0 sc1\n\t"
        "global_load_dwordx4 %5, %8, off offset:832 sc0 sc1\n\t"
        "global_load_dwordx4 %6, %8, off offset:896 sc0 sc1\n\t"
        "global_load_dwordx4 %7, %8, off offset:960 sc0 sc1"
        : "=&v"(q08),"=&v"(q09),"=&v"(q10),"=&v"(q11),
          "=&v"(q12),"=&v"(q13),"=&v"(q14),"=&v"(q15)
        : "v"(rb) : "memory");
      asm volatile(
        "global_load_dwordx4 %0, %8, off offset:1024 sc0 sc1\n\t"
        "global_load_dwordx4 %1, %8, off offset:1088 sc0 sc1\n\t"
        "global_load_dwordx4 %2, %8, off offset:1152 sc0 sc1\n\t"
        "global_load_dwordx4 %3, %8, off offset:1216 sc0 sc1\n\t"
        "global_load_dwordx4 %4, %8, off offset:1280 sc0 sc1\n\t"
        "global_load_dwordx4 %5, %8, off offset:1344 sc0 sc1\n\t"
        "global_load_dwordx4 %6, %8, off offset:1408 sc0 sc1\n\t"
        "global_load_dwordx4 %7, %8, off offset:1472 sc0 sc1"
        : "=&v"(q16),"=&v"(q17),"=&v"(q18),"=&v"(q19),
          "=&v"(q20),"=&v"(q21),"=&v"(q22),"=&v"(q23)
        : "v"(rb) : "memory");
      asm volatile(
        "global_load_dwordx4 %0, %8, off offset:1536 sc0 sc1\n\t"
        "global_load_dwordx4 %1, %8, off offset:1600 sc0 sc1\n\t"
        "global_load_dwordx4 %2, %8, off offset:1664 sc0 sc1\n\t"
        "global_load_dwordx4 %3, %8, off offset:1728 sc0 sc1\n\t"
        "global_load_dwordx4 %4, %8, off offset:1792 sc0 sc1\n\t"
        "global_load_dwordx4 %5, %8, off offset:1856 sc0 sc1\n\t"
        "global_load_dwordx4 %6, %8, off offset:1920 sc0 sc1\n\t"
        "global_load_dwordx4 %7, %8, off offset:1984 sc0 sc1\n\t"
        "s_waitcnt vmcnt(0)"
        : "=&v"(q24),"=&v"(q25),"=&v"(q26),"=&v"(q27),
          "=&v"(q28),"=&v"(q29),"=&v"(q30),"=&v"(q31)
        : "v"(rb) : "memory");
      uint4 fr2[32] = {q00,q01,q02,q03,q04,q05,q06,q07,q08,q09,q10,q11,q12,q13,q14,q15,
                       q16,q17,q18,q19,q20,q21,q22,q23,q24,q25,q26,q27,q28,q29,q30,q31};
#pragma unroll
      for (int kt = 0; kt < 32; ++kt) {
        short8 a   = *(short8*)&fr2[kt];
        short8 bh_ = *(const short8*)(smem + ((2 * 32 + kt) * 64 + lane) * 16);
        acch = __builtin_amdgcn_mfma_f32_16x16x32_bf16(a, bh_, acch, 0, 0, 0);
      }
    }
    // epilogue B: h update in registers; transpose; sc1 store outs; release flag
    {
#pragma unroll
      for (int i = 0; i < 4; ++i) {
        int b = qb + i;
        int tok = toks[b * 512 + t];
        float xh = table[tok * 3072 + 2048 + j0 + j];
        float ht = tanhf(acch[i] + xh);
        float z = (i == 0) ? zz0 : (i == 1) ? zz1 : (i == 2) ? zz2 : zz3;
        h_own[i] = (1.f - z) * ht + z * h_own[i];
        xfer[b * 16 + j] = h_own[i];
      }
      asm volatile("s_waitcnt lgkmcnt(0)" ::: "memory");   // in-wave cross-lane LDS RAW
      int row = lane >> 2, c0 = (lane & 3) * 4;
      float f0 = xfer[row * 16 + c0 + 0], f1 = xfer[row * 16 + c0 + 1];
      float f2 = xfer[row * 16 + c0 + 2], f3 = xfer[row * 16 + c0 + 3];
      st_agent_b64((unsigned long long*)(outs + ((size_t)t * BB + g * 16 + row) * HH + j0 + c0),
                   pack4bf(f0, f1, f2, f3));
      if (t == SS - 1) {
        float4 v4 = {f0, f1, f2, f3};
        *(float4*)(hlast + (size_t)(g * 16 + row) * HH + j0 + c0) = v4;  // fp32, plain
      }
      if (lane == 0) // release: drains this wave's sc1 outs stores first
        __hip_atomic_store(flagsB + g * 64 + wg, t + 1, __ATOMIC_RELEASE, __HIP_MEMORY_SCOPE_AGENT);
    }
  }
}

// logits[b][s][v] = outs[s][b][:] . Wfc[v][:] + b_fc[v]   (fp32 out)
__global__ void __launch_bounds__(256)
logits_kernel(const unsigned short* __restrict__ outs, const float* __restrict__ Wfc,
              const float* __restrict__ bfc, float* __restrict__ out) {
  const int lane = threadIdx.x & 63;
  const int mt = blockIdx.x * 4 + (threadIdx.x >> 6);  // M-tile 0..2047 (M = S*B = 32768)
  const size_t arow = (size_t)(mt * 16 + (lane & 15)) * HH + (lane >> 4) * 8;
  floatx4 zero = {0,0,0,0};
  floatx4 acc[8];
#pragma unroll
  for (int n = 0; n < 8; ++n) acc[n] = zero;
  for (int kt = 0; kt < 32; ++kt) {
    short8 a = *(const short8*)(outs + arow + kt * 32);
#pragma unroll
    for (int n = 0; n < 8; ++n) {
      const float* wsrc = Wfc + (size_t)(n * 16 + (lane & 15)) * HH + kt * 32 + (lane >> 4) * 8;
      float4 f0 = ((const float4*)wsrc)[0];
      float4 f1 = ((const float4*)wsrc)[1];
      short8 b;
      b[0] = (short)f2bf(f0.x); b[1] = (short)f2bf(f0.y);
      b[2] = (short)f2bf(f0.z); b[3] = (short)f2bf(f0.w);
      b[4] = (short)f2bf(f1.x); b[5] = (short)f2bf(f1.y);
      b[6] = (short)f2bf(f1.z); b[7] = (short)f2bf(f1.w);
      acc[n] = __builtin_amdgcn_mfma_f32_16x16x32_bf16(a, b, acc[n], 0, 0, 0);
    }
  }
#pragma unroll
  for (int n = 0; n < 8; ++n) {
    int v = n * 16 + (lane & 15);
    float bias = bfc[v];
#pragma unroll
    for (int i = 0; i < 4; ++i) {
      int m = mt * 16 + (lane >> 4) * 4 + i;
      int s = m >> 6, b = m & 63;
      out[((size_t)b * SS + s) * VV + v] = acc[n][i] + bias;
    }
  }
}

extern "C" void kernel_launch(void* const* d_in, const int* in_sizes, int n_in,
                              void* d_out, int out_size, void* d_ws, size_t ws_size,
                              hipStream_t stream) {
  const int*   x    = (const int*)d_in[0];
  const float* emb  = (const float*)d_in[1];
  const float* W_r  = (const float*)d_in[2];
  const float* U_r  = (const float*)d_in[3];
  const float* b_r  = (const float*)d_in[4];
  const float* W_z  = (const float*)d_in[5];
  const float* U_z  = (const float*)d_in[6];
  const float* b_z  = (const float*)d_in[7];
  const float* W_h  = (const float*)d_in[8];
  const float* U_h  = (const float*)d_in[9];
  const float* b_h  = (const float*)d_in[10];
  const float* W_fc = (const float*)d_in[11];
  const float* b_fc = (const float*)d_in[12];

  char* ws = (char*)d_ws;
  float*          table  = (float*)(ws + WS_TABLE);
  unsigned short* rhbuf  = (unsigned short*)(ws + WS_RH);
  int*            flagsA = (int*)(ws + WS_FLAGS);
  int*            flagsB = (int*)(ws + WS_FLAGS + 1024);
  unsigned short* outs   = (unsigned short*)(ws + WS_OUTS);
  float*          out    = (float*)d_out;
  float*          hlast  = out + (size_t)BB * SS * VV;   // output 1, fp32

  // flags must start at 0 every call (ws is re-poisoned to 0xAA)
  hipMemsetAsync(ws + WS_FLAGS, 0, 2048, stream);

  table_kernel<<<dim3((128 * 3 * 1024) / 256), dim3(256), 0, stream>>>(
      emb, W_r, b_r, W_z, b_z, W_h, b_h, table);

  hipFuncSetAttribute(reinterpret_cast<const void*>(gru_kernel),
                      hipFuncAttributeMaxDynamicSharedMemorySize, LDS_TOTAL);
  void* args[] = {(void*)&x, (void*)&U_r, (void*)&U_z, (void*)&U_h, (void*)&table,
                  (void*)&outs, (void*)&rhbuf, (void*)&hlast, (void*)&flagsA, (void*)&flagsB};
  hipLaunchCooperativeKernel(reinterpret_cast<void*>(gru_kernel), dim3(64), dim3(256),
                             args, (unsigned)LDS_TOTAL, stream);

  logits_kernel<<<dim3(512), dim3(256), 0, stream>>>(outs, W_fc, b_fc, out);
}

// Round 10
// 9413.947 us; speedup vs baseline: 1.3330x; 1.3330x over previous
//
#include <hip/hip_runtime.h>
#include <hip/hip_bf16.h>
#include <stdint.h>

// Problem dims
#define BB 64
#define SS 512
#define EE 256
#define HH 1024
#define VV 128

typedef __attribute__((ext_vector_type(8))) short short8;
typedef __attribute__((ext_vector_type(4))) float floatx4;

// ---- LDS layout (per single-wave WG) ----
#define LDS_UFRAG 0                 // 3 gates * 32 ktiles * 64 lanes * 16B = 98304
#define LDS_TOK   98304             // 16 rows * 512 u8 = 8192 (own group)
#define LDS_XFER  106496            // 1024B transpose tile
#define LDS_TOTAL 107520

// ---- workspace layout (bytes) ----
#define WS_TABLE  0                  // 128*3*1024 fp32 = 1572864
#define WS_RH     1572864            // 64*1024 bf16 = 131072
#define WS_FLAGS  1703936            // flagsA[4*64], flagsB[4*64] ints = 2048 (memset region)
#define WS_OUTS   2097152            // 512*64*1024 bf16 = 67108864

__device__ __forceinline__ unsigned short f2bf(float f) {
  union { float f; unsigned int i; } x; x.f = f;
  unsigned int r = x.i + 0x7fffu + ((x.i >> 16) & 1u);
  return (unsigned short)(r >> 16);
}
__device__ __forceinline__ unsigned long long pack4bf(float a, float b, float c, float d) {
  unsigned int lo = ((unsigned int)f2bf(b) << 16) | f2bf(a);
  unsigned int hi = ((unsigned int)f2bf(d) << 16) | f2bf(c);
  return ((unsigned long long)hi << 32) | lo;
}
// sc1 store: lands at the cross-XCD coherence point, never dirties L2.
__device__ __forceinline__ void st_agent_b64(unsigned long long* p, unsigned long long v) {
  __hip_atomic_store(p, v, __ATOMIC_RELAXED, __HIP_MEMORY_SCOPE_AGENT);
}

// table[v][g][j] = sum_e emb[v][e] * W_g[j][e] + 2*b_g[j]   (fp32 in, fp32 out)
__global__ void __launch_bounds__(256)
table_kernel(const float* __restrict__ emb,
             const float* __restrict__ Wr, const float* __restrict__ br,
             const float* __restrict__ Wz, const float* __restrict__ bz,
             const float* __restrict__ Wh, const float* __restrict__ bh,
             float* __restrict__ table) {
  int id = blockIdx.x * 256 + threadIdx.x;          // 393216 exact
  int v = id / 3072;
  int rem = id - v * 3072;
  int g = rem >> 10;
  int j = rem & 1023;
  const float* W  = (g == 0) ? Wr : (g == 1) ? Wz : Wh;
  const float* bb = (g == 0) ? br : (g == 1) ? bz : bh;
  const float4* ev = (const float4*)(emb + (size_t)v * EE);
  const float4* wv = (const float4*)(W + (size_t)j * EE);
  float acc = 2.f * bb[j];                          // faithful: bias added twice
  for (int e = 0; e < EE / 4; ++e) {
    float4 a = ev[e], b4 = wv[e];
    acc += a.x * b4.x + a.y * b4.y + a.z * b4.z + a.w * b4.w;
  }
  table[id] = acc;
}

// Coalesced bypass poll over a group's 64 flags ("=&v" early-clobber REQUIRED).
__device__ __forceinline__ void poll_flags(const int* flags, int tgt, int lane) {
  const char* fp = (const char*)flags + (lane & 15) * 16;
  for (;;) {
    uint4 f;
    asm volatile("global_load_dwordx4 %0, %1, off sc0 sc1\n\t"
                 "s_waitcnt vmcnt(0)"
                 : "=&v"(f) : "v"(fp) : "memory");
    bool ok = ((int)f.x >= tgt) & ((int)f.y >= tgt) &
              ((int)f.z >= tgt) & ((int)f.w >= tgt);
    if (__all(ok)) break;
    __builtin_amdgcn_s_sleep(1);
  }
}

// Persistent cooperative GRU. 256 WGs x 64 threads (ONE wave per WG).
// wg: group = wg&3 (XCD-pair swizzle under round-robin), col slice = wg>>2.
// Full K=1024 per wave; h/z state in registers; ZERO barriers in the loop.
__global__ void __launch_bounds__(64, 1)
gru_kernel(const int* __restrict__ x,
           const float* __restrict__ Ur, const float* __restrict__ Uz,
           const float* __restrict__ Uh,
           const float* __restrict__ table,
           unsigned short* __restrict__ outs,     // [S][B][H] bf16 (sc1-written, cached reads)
           unsigned short* __restrict__ rhbuf,    // [B][H] bf16 (sc1-written, bypass reads)
           float* __restrict__ hlast,             // [B][H] fp32 -> d_out tail
           int* __restrict__ flagsA, int* __restrict__ flagsB) {  // [4][64]
  extern __shared__ char smem[];
  const int lane = threadIdx.x;
  const int wg = blockIdx.x;
  const int group = wg & 3;          // swizzle: XCD = wg%8 (conjecture) -> XCDs {g, g+4}
  const int col = wg >> 2;
  const int j0 = col << 4;
  const int j = lane & 15;
  const int qb = (lane >> 4) * 4;    // C-layout: reg i holds row qb+i, col j

  unsigned char* toks = (unsigned char*)(smem + LDS_TOK);   // [16][512], own group
  float* xfer = (float*)(smem + LDS_XFER);

  // ---- init (single wave, no barriers needed): U -> LDS bf16 B-frags; tokens ----
  {
    const float* Us[3] = {Ur, Uz, Uh};
    for (int c = 0; c < 96; ++c) {
      int gt = c >> 5, kt = c & 31;
      // B-frag: lane holds U[j0+j][kt*32 + (lane>>4)*8 + 0..7]
      const float* src = Us[gt] + (size_t)(j0 + j) * HH + kt * 32 + (lane >> 4) * 8;
      float4 f0 = ((const float4*)src)[0];
      float4 f1 = ((const float4*)src)[1];
      short8 frag;
      frag[0] = (short)f2bf(f0.x); frag[1] = (short)f2bf(f0.y);
      frag[2] = (short)f2bf(f0.z); frag[3] = (short)f2bf(f0.w);
      frag[4] = (short)f2bf(f1.x); frag[5] = (short)f2bf(f1.y);
      frag[6] = (short)f2bf(f1.z); frag[7] = (short)f2bf(f1.w);
      *(short8*)(smem + ((gt * 32 + kt) * 64 + lane) * 16) = frag;
    }
    for (int i = lane; i < 16 * SS; i += 64) {
      int b = i >> 9, tt = i & 511;
      toks[i] = (unsigned char)x[(size_t)(group * 16 + b) * SS + tt];
    }
  }

  floatx4 h_own = {0, 0, 0, 0};      // fp32 master copy in registers (C-layout)
  float zz0, zz1, zz2, zz3;

  for (int t = 0; t < SS; ++t) {
    // ================= phase A : r, z (full K, this wave) =================
    floatx4 accr = {0,0,0,0}, accz = {0,0,0,0};
    if (t > 0) {
      poll_flags(flagsB + group * 64, t, lane);
      // A-frags straight from global, cached (write-once lines; 32 WGs of this
      // group per XCD share these reads in local L2 if the swizzle holds).
      const unsigned short* hb =
          outs + ((size_t)(t - 1) * BB + group * 16 + j) * HH + (lane >> 4) * 8;
      uint4 fr[32];                   // 128 VGPRs — fine at 1 wave/CU (bounds 64,1)
#pragma unroll
      for (int kt = 0; kt < 32; ++kt) fr[kt] = *(const uint4*)(hb + kt * 32);
#pragma unroll
      for (int kt = 0; kt < 32; ++kt) {
        short8 a   = *(short8*)&fr[kt];
        short8 br_ = *(const short8*)(smem + ((0 * 32 + kt) * 64 + lane) * 16);
        short8 bz_ = *(const short8*)(smem + ((1 * 32 + kt) * 64 + lane) * 16);
        accr = __builtin_amdgcn_mfma_f32_16x16x32_bf16(a, br_, accr, 0, 0, 0);
        accz = __builtin_amdgcn_mfma_f32_16x16x32_bf16(a, bz_, accz, 0, 0, 0);
      }
    }
    // epilogue A: r,z; rh -> xfer transpose -> packed sc1 store; release flag
    {
      float rh0, rh1, rh2, rh3;
#pragma unroll
      for (int i = 0; i < 4; ++i) {
        int b = qb + i;
        int tok = toks[b * 512 + t];
        float xr = table[tok * 3072 + j0 + j];
        float xz = table[tok * 3072 + 1024 + j0 + j];
        float r = 1.f / (1.f + __expf(-(accr[i] + xr)));
        float z = 1.f / (1.f + __expf(-(accz[i] + xz)));
        float rh = r * h_own[i];
        if (i == 0) { zz0 = z; rh0 = rh; } else if (i == 1) { zz1 = z; rh1 = rh; }
        else if (i == 2) { zz2 = z; rh2 = rh; } else { zz3 = z; rh3 = rh; }
      }
      xfer[(qb + 0) * 16 + j] = rh0;
      xfer[(qb + 1) * 16 + j] = rh1;
      xfer[(qb + 2) * 16 + j] = rh2;
      xfer[(qb + 3) * 16 + j] = rh3;
      asm volatile("s_waitcnt lgkmcnt(0)" ::: "memory");   // in-wave cross-lane LDS RAW
      int row = lane >> 2, c0 = (lane & 3) * 4;
      unsigned long long pk = pack4bf(xfer[row * 16 + c0 + 0], xfer[row * 16 + c0 + 1],
                                      xfer[row * 16 + c0 + 2], xfer[row * 16 + c0 + 3]);
      st_agent_b64((unsigned long long*)(rhbuf + (size_t)(group * 16 + row) * HH + j0 + c0), pk);
      if (lane == 0)   // release: vmcnt(0) drains this wave's sc1 stores first
        __hip_atomic_store(flagsA + group * 64 + col, t + 1, __ATOMIC_RELEASE, __HIP_MEMORY_SCOPE_AGENT);
    }

    // ================= phase B : h_tilde, h_new =================
    poll_flags(flagsA + group * 64, t + 1, lane);
    floatx4 acch = {0,0,0,0};
    {
      // rh addresses reused every step -> bypass L2: 32x dwordx4 sc0 sc1, one drain.
      const char* rb = (const char*)(rhbuf + (size_t)(group * 16 + j) * HH + (lane >> 4) * 8);
      uint4 q00,q01,q02,q03,q04,q05,q06,q07,q08,q09,q10,q11,q12,q13,q14,q15;
      uint4 q16,q17,q18,q19,q20,q21,q22,q23,q24,q25,q26,q27,q28,q29,q30,q31;
      asm volatile(
        "global_load_dwordx4 %0, %8, off sc0 sc1\n\t"
        "global_load_dwordx4 %1, %8, off offset:64 sc0 sc1\n\t"
        "global_load_dwordx4 %2, %8, off offset:128 sc0 sc1\n\t"
        "global_load_dwordx4 %3, %8, off offset:192 sc0 sc1\n\t"
        "global_load_dwordx4 %4, %8, off offset:256 sc0 sc1\n\t"
        "global_load_dwordx4 %5, %8, off offset:320 sc0 sc1\n\t"
        "global_load_dwordx4 %6, %8, off offset:384 sc0 sc1\n\t"
        "global_load_dwordx4 %7, %8, off offset:448 sc0 sc1"
        : "=&v"(q00),"=&v"(q01),"=&v"(q02),"=&v"(q03),
          "=&v"(q04),"=&v"(q05),"=&v"(q06),"=&v"(q07)
        : "v"(rb) : "memory");
      asm volatile(
        "global_load_dwordx4 %0, %8, off offset:512 sc0 sc1\n\t"
        "global_load_dwordx4 %1, %8, off offset:576 sc0 sc1\n\t"
        "global_load_dwordx4 %2, %8, off offset:640 sc0 sc1\n\t"
        "global_load_dwordx4 %3, %8, off offset:704 sc0 sc1\n\t"
        "global_load_dwordx4 %4, %8, off offset:768 sc0 sc1\n\t"
        "global_load_dwordx4 %5, %8, off offset:832 sc0 sc1\n\t"
        "global_load_dwordx4 %6, %8, off offset:896 sc0 sc1\n\t"
        "global_load_dwordx4 %7, %8, off offset:960 sc0 sc1"
        : "=&v"(q08),"=&v"(q09),"=&v"(q10),"=&v"(q11),
          "=&v"(q12),"=&v"(q13),"=&v"(q14),"=&v"(q15)
        : "v"(rb) : "memory");
      asm volatile(
        "global_load_dwordx4 %0, %8, off offset:1024 sc0 sc1\n\t"
        "global_load_dwordx4 %1, %8, off offset:1088 sc0 sc1\n\t"
        "global_load_dwordx4 %2, %8, off offset:1152 sc0 sc1\n\t"
        "global_load_dwordx4 %3, %8, off offset:1216 sc0 sc1\n\t"
        "global_load_dwordx4 %4, %8, off offset:1280 sc0 sc1\n\t"
        "global_load_dwordx4 %5, %8, off offset:1344 sc0 sc1\n\t"
        "global_load_dwordx4 %6, %8, off offset:1408 sc0 sc1\n\t"
        "global_load_dwordx4 %7, %8, off offset:1472 sc0 sc1"
        : "=&v"(q16),"=&v"(q17),"=&v"(q18),"=&v"(q19),
          "=&v"(q20),"=&v"(q21),"=&v"(q22),"=&v"(q23)
        : "v"(rb) : "memory");
      asm volatile(
        "global_load_dwordx4 %0, %8, off offset:1536 sc0 sc1\n\t"
        "global_load_dwordx4 %1, %8, off offset:1600 sc0 sc1\n\t"
        "global_load_dwordx4 %2, %8, off offset:1664 sc0 sc1\n\t"
        "global_load_dwordx4 %3, %8, off offset:1728 sc0 sc1\n\t"
        "global_load_dwordx4 %4, %8, off offset:1792 sc0 sc1\n\t"
        "global_load_dwordx4 %5, %8, off offset:1856 sc0 sc1\n\t"
        "global_load_dwordx4 %6, %8, off offset:1920 sc0 sc1\n\t"
        "global_load_dwordx4 %7, %8, off offset:1984 sc0 sc1\n\t"
        "s_waitcnt vmcnt(0)"
        : "=&v"(q24),"=&v"(q25),"=&v"(q26),"=&v"(q27),
          "=&v"(q28),"=&v"(q29),"=&v"(q30),"=&v"(q31)
        : "v"(rb) : "memory");
      uint4 fr2[32] = {q00,q01,q02,q03,q04,q05,q06,q07,q08,q09,q10,q11,q12,q13,q14,q15,
                       q16,q17,q18,q19,q20,q21,q22,q23,q24,q25,q26,q27,q28,q29,q30,q31};
#pragma unroll
      for (int kt = 0; kt < 32; ++kt) {
        short8 a   = *(short8*)&fr2[kt];
        short8 bh_ = *(const short8*)(smem + ((2 * 32 + kt) * 64 + lane) * 16);
        acch = __builtin_amdgcn_mfma_f32_16x16x32_bf16(a, bh_, acch, 0, 0, 0);
      }
    }
    // epilogue B: h update in registers; transpose; sc1 store outs; release flag
    {
#pragma unroll
      for (int i = 0; i < 4; ++i) {
        int b = qb + i;
        int tok = toks[b * 512 + t];
        float xh = table[tok * 3072 + 2048 + j0 + j];
        float ht = tanhf(acch[i] + xh);
        float z = (i == 0) ? zz0 : (i == 1) ? zz1 : (i == 2) ? zz2 : zz3;
        h_own[i] = (1.f - z) * ht + z * h_own[i];
        xfer[b * 16 + j] = h_own[i];
      }
      asm volatile("s_waitcnt lgkmcnt(0)" ::: "memory");   // in-wave cross-lane LDS RAW
      int row = lane >> 2, c0 = (lane & 3) * 4;
      float f0 = xfer[row * 16 + c0 + 0], f1 = xfer[row * 16 + c0 + 1];
      float f2 = xfer[row * 16 + c0 + 2], f3 = xfer[row * 16 + c0 + 3];
      st_agent_b64((unsigned long long*)(outs + ((size_t)t * BB + group * 16 + row) * HH + j0 + c0),
                   pack4bf(f0, f1, f2, f3));
      if (t == SS - 1) {
        float4 v4 = {f0, f1, f2, f3};
        *(float4*)(hlast + (size_t)(group * 16 + row) * HH + j0 + c0) = v4;  // fp32, plain
      }
      if (lane == 0) // release: drains this wave's sc1 outs stores first
        __hip_atomic_store(flagsB + group * 64 + col, t + 1, __ATOMIC_RELEASE, __HIP_MEMORY_SCOPE_AGENT);
    }
  }
}

// logits[b][s][v] = outs[s][b][:] . Wfc[v][:] + b_fc[v]   (fp32 out)
__global__ void __launch_bounds__(256)
logits_kernel(const unsigned short* __restrict__ outs, const float* __restrict__ Wfc,
              const float* __restrict__ bfc, float* __restrict__ out) {
  const int lane = threadIdx.x & 63;
  const int mt = blockIdx.x * 4 + (threadIdx.x >> 6);  // M-tile 0..2047 (M = S*B = 32768)
  const size_t arow = (size_t)(mt * 16 + (lane & 15)) * HH + (lane >> 4) * 8;
  floatx4 zero = {0,0,0,0};
  floatx4 acc[8];
#pragma unroll
  for (int n = 0; n < 8; ++n) acc[n] = zero;
  for (int kt = 0; kt < 32; ++kt) {
    short8 a = *(const short8*)(outs + arow + kt * 32);
#pragma unroll
    for (int n = 0; n < 8; ++n) {
      const float* wsrc = Wfc + (size_t)(n * 16 + (lane & 15)) * HH + kt * 32 + (lane >> 4) * 8;
      float4 f0 = ((const float4*)wsrc)[0];
      float4 f1 = ((const float4*)wsrc)[1];
      short8 b;
      b[0] = (short)f2bf(f0.x); b[1] = (short)f2bf(f0.y);
      b[2] = (short)f2bf(f0.z); b[3] = (short)f2bf(f0.w);
      b[4] = (short)f2bf(f1.x); b[5] = (short)f2bf(f1.y);
      b[6] = (short)f2bf(f1.z); b[7] = (short)f2bf(f1.w);
      acc[n] = __builtin_amdgcn_mfma_f32_16x16x32_bf16(a, b, acc[n], 0, 0, 0);
    }
  }
#pragma unroll
  for (int n = 0; n < 8; ++n) {
    int v = n * 16 + (lane & 15);
    float bias = bfc[v];
#pragma unroll
    for (int i = 0; i < 4; ++i) {
      int m = mt * 16 + (lane >> 4) * 4 + i;
      int s = m >> 6, b = m & 63;
      out[((size_t)b * SS + s) * VV + v] = acc[n][i] + bias;
    }
  }
}

extern "C" void kernel_launch(void* const* d_in, const int* in_sizes, int n_in,
                              void* d_out, int out_size, void* d_ws, size_t ws_size,
                              hipStream_t stream) {
  const int*   x    = (const int*)d_in[0];
  const float* emb  = (const float*)d_in[1];
  const float* W_r  = (const float*)d_in[2];
  const float* U_r  = (const float*)d_in[3];
  const float* b_r  = (const float*)d_in[4];
  const float* W_z  = (const float*)d_in[5];
  const float* U_z  = (const float*)d_in[6];
  const float* b_z  = (const float*)d_in[7];
  const float* W_h  = (const float*)d_in[8];
  const float* U_h  = (const float*)d_in[9];
  const float* b_h  = (const float*)d_in[10];
  const float* W_fc = (const float*)d_in[11];
  const float* b_fc = (const float*)d_in[12];

  char* ws = (char*)d_ws;
  float*          table  = (float*)(ws + WS_TABLE);
  unsigned short* rhbuf  = (unsigned short*)(ws + WS_RH);
  int*            flagsA = (int*)(ws + WS_FLAGS);
  int*            flagsB = (int*)(ws + WS_FLAGS + 1024);
  unsigned short* outs   = (unsigned short*)(ws + WS_OUTS);
  float*          out    = (float*)d_out;
  float*          hlast  = out + (size_t)BB * SS * VV;   // output 1, fp32

  // flags must start at 0 every call (ws is re-poisoned to 0xAA)
  hipMemsetAsync(ws + WS_FLAGS, 0, 2048, stream);

  table_kernel<<<dim3((128 * 3 * 1024) / 256), dim3(256), 0, stream>>>(
      emb, W_r, b_r, W_z, b_z, W_h, b_h, table);

  hipFuncSetAttribute(reinterpret_cast<const void*>(gru_kernel),
                      hipFuncAttributeMaxDynamicSharedMemorySize, LDS_TOTAL);
  void* args[] = {(void*)&x, (void*)&U_r, (void*)&U_z, (void*)&U_h, (void*)&table,
                  (void*)&outs, (void*)&rhbuf, (void*)&hlast, (void*)&flagsA, (void*)&flagsB};
  hipLaunchCooperativeKernel(reinterpret_cast<void*>(gru_kernel), dim3(256), dim3(64),
                             args, (unsigned)LDS_TOTAL, stream);

  logits_kernel<<<dim3(512), dim3(256), 0, stream>>>(outs, W_fc, b_fc, out);
}